// Round 3
// baseline (546.978 us; speedup 1.0000x reference)
//
#include <hip/hip_runtime.h>
#include <math.h>

// ---------------------------------------------------------------------------
// GAT 2-layer forward. N=100k nodes, E=1.6M edges + N self-loops.
// CSR-by-dst build (hist -> scan -> scatter), then per-node wave aggregation.
// R1: 4-edge ILP batching in agg kernels.
// R3: bf16 storage for gathered feature rows (h1: 256->128 B/edge,
//     h2lin: 128->64 B/edge) + 8-edge ILP in agg1. Logits/weights stay fp32.
// ---------------------------------------------------------------------------

static __device__ __forceinline__ unsigned short f2bf(float f) {
    unsigned int u = __float_as_uint(f);
    unsigned int r = (u + 0x7fffu + ((u >> 16) & 1u)) >> 16;   // RNE
    return (unsigned short)r;
}
static __device__ __forceinline__ float bf2f(unsigned short b) {
    return __uint_as_float(((unsigned int)b) << 16);
}

__global__ void k_init(int* __restrict__ cnt, int* __restrict__ cur, int n) {
    int i = blockIdx.x * blockDim.x + threadIdx.x;
    if (i < n) { cnt[i] = 1; cur[i] = 0; }   // cnt starts at 1: self-loop
}

__global__ void k_hist(const int* __restrict__ ei, int E, int* __restrict__ cnt) {
    int i = blockIdx.x * blockDim.x + threadIdx.x;
    if (i < E) atomicAdd(&cnt[ei[E + i]], 1);     // ei[1][i] = dst
}

// Per-block (chunk=2048) exclusive scan, block totals to bsum.
__global__ void k_scan1(const int* __restrict__ cnt, int* __restrict__ off,
                        int* __restrict__ bsum, int n) {
    __shared__ int lds[256];
    int t = threadIdx.x;
    int base = blockIdx.x * 2048 + t * 8;
    int v[8]; int s = 0;
#pragma unroll
    for (int j = 0; j < 8; ++j) { int idx = base + j; v[j] = (idx < n) ? cnt[idx] : 0; s += v[j]; }
    lds[t] = s; __syncthreads();
    int inc = s;
    for (int d = 1; d < 256; d <<= 1) {
        int y = (t >= d) ? lds[t - d] : 0;
        __syncthreads();
        inc += y; lds[t] = inc;
        __syncthreads();
    }
    int run = inc - s;
#pragma unroll
    for (int j = 0; j < 8; ++j) { int idx = base + j; if (idx < n) off[idx] = run; run += v[j]; }
    if (t == 255) bsum[blockIdx.x] = inc;
}

__global__ void k_scan2(int* __restrict__ bsum, int nb) {
    __shared__ int lds[1024];
    int t = threadIdx.x;
    int v = (t < nb) ? bsum[t] : 0;
    lds[t] = v; __syncthreads();
    int inc = v;
    for (int d = 1; d < 1024; d <<= 1) {
        int y = (t >= d) ? lds[t - d] : 0;
        __syncthreads();
        inc += y; lds[t] = inc;
        __syncthreads();
    }
    if (t < nb) bsum[t] = inc - v;   // exclusive block prefix
}

__global__ void k_scan3(int* __restrict__ off, const int* __restrict__ bsum, int n, int total) {
    int i = blockIdx.x * blockDim.x + threadIdx.x;
    if (i < n) off[i] += bsum[i / 2048];
    if (i == 0) off[n] = total;
}

__global__ void k_scatter(const int* __restrict__ ei, int E, int n,
                          const int* __restrict__ off, int* __restrict__ cur,
                          int* __restrict__ csr_src) {
    int i = blockIdx.x * blockDim.x + threadIdx.x;
    int total = E + n;
    if (i >= total) return;
    int s, d;
    if (i < E) { s = ei[i]; d = ei[E + i]; } else { s = d = i - E; }
    int pos = off[d] + atomicAdd(&cur[d], 1);
    csr_src[pos] = s;
}

// h1 = x @ W1  [N,64] stored bf16; attention logit halves as1/ad1 [N,2] fp32.
__global__ void k_gemm1(const float* __restrict__ x, const float* __restrict__ W1,
                        const float* __restrict__ a_src1, const float* __restrict__ a_dst1,
                        unsigned short* __restrict__ h1b, float* __restrict__ as1,
                        float* __restrict__ ad1, int n) {
    __shared__ float w_lds[64 * 64];
    int t = threadIdx.x;
    for (int i = t; i < 4096; i += 256) w_lds[i] = W1[i];
    __syncthreads();
    int lane = t & 63, wid = t >> 6;
    int head = lane >> 5, cc = lane & 31;
    float asv = a_src1[head * 32 + cc], adv = a_dst1[head * 32 + cc];
    int nwaves = gridDim.x * 4;
    for (int node = blockIdx.x * 4 + wid; node < n; node += nwaves) {
        float xv = x[node * 64 + lane];
        float acc = 0.f;
#pragma unroll
        for (int k = 0; k < 64; ++k) {
            float xk = __shfl(xv, k, 64);
            acc = fmaf(xk, w_lds[k * 64 + lane], acc);
        }
        h1b[node * 64 + lane] = f2bf(acc);
        float ps = acc * asv, pd = acc * adv;
        for (int d = 16; d > 0; d >>= 1) { ps += __shfl_xor(ps, d, 64); pd += __shfl_xor(pd, d, 64); }
        if (cc == 0) { as1[node * 2 + head] = ps; ad1[node * 2 + head] = pd; }
    }
}

// Layer-1 aggregation + bias + exact GELU + (x2 @ W2) + layer-2 logits.
// One wave per node; 8-edge ILP batching; bf16 feature gathers.
__global__ void k_agg1(const unsigned short* __restrict__ h1b, const float* __restrict__ as1,
                       const float* __restrict__ ad1, const float* __restrict__ b1,
                       const float* __restrict__ W2, const float* __restrict__ a_src2,
                       const float* __restrict__ a_dst2,
                       const int* __restrict__ off, const int* __restrict__ csr_src,
                       unsigned short* __restrict__ h2b, float* __restrict__ as2,
                       float* __restrict__ ad2, int n) {
    __shared__ float w2_lds[64 * 32];
    __shared__ float b1_lds[64];
    __shared__ float av2_lds[64];
    int t = threadIdx.x;
    for (int i = t; i < 2048; i += 256) w2_lds[i] = W2[i];
    if (t < 64) b1_lds[t] = b1[t];
    if (t < 32) av2_lds[t] = a_src2[t];
    else if (t < 64) av2_lds[t] = a_dst2[t - 32];
    __syncthreads();
    int lane = t & 63, wid = t >> 6;
    int head = lane >> 5, cc = lane & 31;
    int nwaves = gridDim.x * 4;
    for (int node = blockIdx.x * 4 + wid; node < n; node += nwaves) {
        float adh = ad1[node * 2 + head];
        float acc = 0.f, wsum = 0.f;
        int p = off[node], pe = off[node + 1];
        for (; p + 8 <= pe; p += 8) {
            int s0 = csr_src[p + 0], s1 = csr_src[p + 1];
            int s2 = csr_src[p + 2], s3 = csr_src[p + 3];
            int s4 = csr_src[p + 4], s5 = csr_src[p + 5];
            int s6 = csr_src[p + 6], s7 = csr_src[p + 7];
            float a0 = as1[s0 * 2 + head], a1 = as1[s1 * 2 + head];
            float a2 = as1[s2 * 2 + head], a3 = as1[s3 * 2 + head];
            float a4 = as1[s4 * 2 + head], a5 = as1[s5 * 2 + head];
            float a6 = as1[s6 * 2 + head], a7 = as1[s7 * 2 + head];
            unsigned short u0 = h1b[s0 * 64 + lane], u1 = h1b[s1 * 64 + lane];
            unsigned short u2 = h1b[s2 * 64 + lane], u3 = h1b[s3 * 64 + lane];
            unsigned short u4 = h1b[s4 * 64 + lane], u5 = h1b[s5 * 64 + lane];
            unsigned short u6 = h1b[s6 * 64 + lane], u7 = h1b[s7 * 64 + lane];
            float e0 = a0 + adh; e0 = e0 > 0.f ? e0 : 0.2f * e0;
            float e1 = a1 + adh; e1 = e1 > 0.f ? e1 : 0.2f * e1;
            float e2 = a2 + adh; e2 = e2 > 0.f ? e2 : 0.2f * e2;
            float e3 = a3 + adh; e3 = e3 > 0.f ? e3 : 0.2f * e3;
            float e4 = a4 + adh; e4 = e4 > 0.f ? e4 : 0.2f * e4;
            float e5 = a5 + adh; e5 = e5 > 0.f ? e5 : 0.2f * e5;
            float e6 = a6 + adh; e6 = e6 > 0.f ? e6 : 0.2f * e6;
            float e7 = a7 + adh; e7 = e7 > 0.f ? e7 : 0.2f * e7;
            float w0 = __expf(e0), w1 = __expf(e1), w2 = __expf(e2), w3 = __expf(e3);
            float w4 = __expf(e4), w5 = __expf(e5), w6 = __expf(e6), w7 = __expf(e7);
            wsum += ((w0 + w1) + (w2 + w3)) + ((w4 + w5) + (w6 + w7));
            acc = fmaf(w0, bf2f(u0), acc);
            acc = fmaf(w1, bf2f(u1), acc);
            acc = fmaf(w2, bf2f(u2), acc);
            acc = fmaf(w3, bf2f(u3), acc);
            acc = fmaf(w4, bf2f(u4), acc);
            acc = fmaf(w5, bf2f(u5), acc);
            acc = fmaf(w6, bf2f(u6), acc);
            acc = fmaf(w7, bf2f(u7), acc);
        }
        for (; p < pe; ++p) {
            int s = csr_src[p];
            float e = as1[s * 2 + head] + adh;
            e = e > 0.f ? e : 0.2f * e;
            float w = __expf(e);
            wsum += w;
            acc = fmaf(w, bf2f(h1b[s * 64 + lane]), acc);
        }
        float g = acc / wsum + b1_lds[lane];
        g = 0.5f * g * (1.0f + erff(g * 0.70710678118654752f));   // exact GELU
        // h2lin = gelu_out @ W2 via full-wave broadcast
        float acc2 = 0.f;
#pragma unroll
        for (int k = 0; k < 64; ++k) {
            float gk = __shfl(g, k, 64);
            acc2 = fmaf(gk, w2_lds[k * 32 + cc], acc2);
        }
        float ps = acc2 * av2_lds[cc];
        float pd = acc2 * av2_lds[32 + cc];
        for (int d = 16; d > 0; d >>= 1) { ps += __shfl_xor(ps, d, 64); pd += __shfl_xor(pd, d, 64); }
        if (lane < 32) h2b[node * 32 + cc] = f2bf(acc2);
        if (lane == 0) { as2[node] = ps; ad2[node] = pd; }
    }
}

// Layer-2 aggregation: one wave per node, half-wave per edge stream,
// 4 edges per half-wave batch (8 edges in flight per wave); bf16 gathers.
__global__ void k_agg2(const unsigned short* __restrict__ h2b, const float* __restrict__ as2,
                       const float* __restrict__ ad2, const float* __restrict__ b2,
                       const int* __restrict__ off, const int* __restrict__ csr_src,
                       float* __restrict__ out, int n) {
    int t = threadIdx.x;
    int lane = t & 63, wid = t >> 6;
    int eh = lane >> 5, cc = lane & 31;
    int nwaves = gridDim.x * 4;
    for (int node = blockIdx.x * 4 + wid; node < n; node += nwaves) {
        float adv = ad2[node];
        float acc = 0.f, wsum = 0.f;
        int p = off[node] + eh, pe = off[node + 1];
        for (; p + 6 < pe; p += 8) {
            int s0 = csr_src[p + 0];
            int s1 = csr_src[p + 2];
            int s2 = csr_src[p + 4];
            int s3 = csr_src[p + 6];
            float a0 = as2[s0];
            float a1 = as2[s1];
            float a2 = as2[s2];
            float a3 = as2[s3];
            unsigned short u0 = h2b[s0 * 32 + cc];
            unsigned short u1 = h2b[s1 * 32 + cc];
            unsigned short u2 = h2b[s2 * 32 + cc];
            unsigned short u3 = h2b[s3 * 32 + cc];
            float e0 = a0 + adv; e0 = e0 > 0.f ? e0 : 0.2f * e0;
            float e1 = a1 + adv; e1 = e1 > 0.f ? e1 : 0.2f * e1;
            float e2 = a2 + adv; e2 = e2 > 0.f ? e2 : 0.2f * e2;
            float e3 = a3 + adv; e3 = e3 > 0.f ? e3 : 0.2f * e3;
            float w0 = __expf(e0), w1 = __expf(e1), w2 = __expf(e2), w3 = __expf(e3);
            wsum += (w0 + w1) + (w2 + w3);
            acc = fmaf(w0, bf2f(u0), acc);
            acc = fmaf(w1, bf2f(u1), acc);
            acc = fmaf(w2, bf2f(u2), acc);
            acc = fmaf(w3, bf2f(u3), acc);
        }
        for (; p < pe; p += 2) {
            int s = csr_src[p];
            float e = as2[s] + adv;
            e = e > 0.f ? e : 0.2f * e;
            float w = __expf(e);
            wsum += w;
            acc = fmaf(w, bf2f(h2b[s * 32 + cc]), acc);
        }
        acc += __shfl_xor(acc, 32, 64);
        wsum += __shfl_xor(wsum, 32, 64);
        if (lane < 32) out[node * 32 + cc] = acc / wsum + b2[cc];
    }
}

extern "C" void kernel_launch(void* const* d_in, const int* in_sizes, int n_in,
                              void* d_out, int out_size, void* d_ws, size_t ws_size,
                              hipStream_t stream) {
    const float* x      = (const float*)d_in[0];
    const int*   ei     = (const int*)d_in[1];
    const float* W1     = (const float*)d_in[2];
    const float* a_src1 = (const float*)d_in[3];
    const float* a_dst1 = (const float*)d_in[4];
    const float* b1     = (const float*)d_in[5];
    const float* W2     = (const float*)d_in[6];
    const float* a_src2 = (const float*)d_in[7];
    const float* a_dst2 = (const float*)d_in[8];
    const float* b2     = (const float*)d_in[9];
    float* out = (float*)d_out;

    int n   = in_sizes[0] / 64;
    int E   = in_sizes[1] / 2;
    int tot = E + n;

    char* w = (char*)d_ws;
    int* off  = (int*)w; w += sizeof(int) * (size_t)(n + 1);
    int* cnt  = (int*)w; w += sizeof(int) * (size_t)n;
    int* cur  = (int*)w; w += sizeof(int) * (size_t)n;
    int* bsum = (int*)w; w += sizeof(int) * 1024;
    int* csr  = (int*)w; w += sizeof(int) * (size_t)tot;
    unsigned short* h1b = (unsigned short*)w; w += sizeof(unsigned short) * (size_t)n * 64;
    float* as1 = (float*)w; w += sizeof(float) * (size_t)n * 2;
    float* ad1 = (float*)w; w += sizeof(float) * (size_t)n * 2;
    unsigned short* h2b = (unsigned short*)w; w += sizeof(unsigned short) * (size_t)n * 32;
    float* as2v = (float*)w; w += sizeof(float) * (size_t)n;
    float* ad2v = (float*)w; w += sizeof(float) * (size_t)n;

    k_init<<<(n + 255) / 256, 256, 0, stream>>>(cnt, cur, n);
    k_hist<<<(E + 255) / 256, 256, 0, stream>>>(ei, E, cnt);
    int nb = (n + 2047) / 2048;
    k_scan1<<<nb, 256, 0, stream>>>(cnt, off, bsum, n);
    k_scan2<<<1, 1024, 0, stream>>>(bsum, nb);
    k_scan3<<<(n + 255) / 256, 256, 0, stream>>>(off, bsum, n, tot);
    k_scatter<<<(tot + 255) / 256, 256, 0, stream>>>(ei, E, n, off, cur, csr);
    k_gemm1<<<1024, 256, 0, stream>>>(x, W1, a_src1, a_dst1, h1b, as1, ad1, n);
    k_agg1<<<2048, 256, 0, stream>>>(h1b, as1, ad1, b1, W2, a_src2, a_dst2,
                                     off, csr, h2b, as2v, ad2v, n);
    k_agg2<<<2048, 256, 0, stream>>>(h2b, as2v, ad2v, b2, off, csr, out, n);
}

// Round 4
// 420.662 us; speedup vs baseline: 1.3003x; 1.3003x over previous
//
#include <hip/hip_runtime.h>
#include <math.h>

// ---------------------------------------------------------------------------
// GAT 2-layer forward. N=100k nodes, E=1.6M edges + N self-loops.
// CSR-by-dst build (hist -> scan -> scatter), then per-node wave aggregation.
// R3: bf16 feature storage (h1: 128 B/row, h2: 64 B/row).
// R4: packed-dword gathers -- half-wave per row in agg1 (2 edges/load-instr),
//     quarter-wave per row in agg2 (4 edges/load-instr); 8-edge batches;
//     __launch_bounds__(256,4) so the batch stays live in registers
//     (R3's 8-deep ushort version serialized at VGPR=64).
// ---------------------------------------------------------------------------

static __device__ __forceinline__ unsigned short f2bf(float f) {
    unsigned int u = __float_as_uint(f);
    unsigned int r = (u + 0x7fffu + ((u >> 16) & 1u)) >> 16;   // RNE
    return (unsigned short)r;
}
static __device__ __forceinline__ float bf_lo(unsigned int w) {
    return __uint_as_float(w << 16);
}
static __device__ __forceinline__ float bf_hi(unsigned int w) {
    return __uint_as_float(w & 0xffff0000u);
}

__global__ void k_init(int* __restrict__ cnt, int* __restrict__ cur, int n) {
    int i = blockIdx.x * blockDim.x + threadIdx.x;
    if (i < n) { cnt[i] = 1; cur[i] = 0; }   // cnt starts at 1: self-loop
}

__global__ void k_hist(const int* __restrict__ ei, int E, int* __restrict__ cnt) {
    int i = blockIdx.x * blockDim.x + threadIdx.x;
    if (i < E) atomicAdd(&cnt[ei[E + i]], 1);     // ei[1][i] = dst
}

// Per-block (chunk=2048) exclusive scan, block totals to bsum.
__global__ void k_scan1(const int* __restrict__ cnt, int* __restrict__ off,
                        int* __restrict__ bsum, int n) {
    __shared__ int lds[256];
    int t = threadIdx.x;
    int base = blockIdx.x * 2048 + t * 8;
    int v[8]; int s = 0;
#pragma unroll
    for (int j = 0; j < 8; ++j) { int idx = base + j; v[j] = (idx < n) ? cnt[idx] : 0; s += v[j]; }
    lds[t] = s; __syncthreads();
    int inc = s;
    for (int d = 1; d < 256; d <<= 1) {
        int y = (t >= d) ? lds[t - d] : 0;
        __syncthreads();
        inc += y; lds[t] = inc;
        __syncthreads();
    }
    int run = inc - s;
#pragma unroll
    for (int j = 0; j < 8; ++j) { int idx = base + j; if (idx < n) off[idx] = run; run += v[j]; }
    if (t == 255) bsum[blockIdx.x] = inc;
}

__global__ void k_scan2(int* __restrict__ bsum, int nb) {
    __shared__ int lds[1024];
    int t = threadIdx.x;
    int v = (t < nb) ? bsum[t] : 0;
    lds[t] = v; __syncthreads();
    int inc = v;
    for (int d = 1; d < 1024; d <<= 1) {
        int y = (t >= d) ? lds[t - d] : 0;
        __syncthreads();
        inc += y; lds[t] = inc;
        __syncthreads();
    }
    if (t < nb) bsum[t] = inc - v;   // exclusive block prefix
}

__global__ void k_scan3(int* __restrict__ off, const int* __restrict__ bsum, int n, int total) {
    int i = blockIdx.x * blockDim.x + threadIdx.x;
    if (i < n) off[i] += bsum[i / 2048];
    if (i == 0) off[n] = total;
}

__global__ void k_scatter(const int* __restrict__ ei, int E, int n,
                          const int* __restrict__ off, int* __restrict__ cur,
                          int* __restrict__ csr_src) {
    int i = blockIdx.x * blockDim.x + threadIdx.x;
    int total = E + n;
    if (i >= total) return;
    int s, d;
    if (i < E) { s = ei[i]; d = ei[E + i]; } else { s = d = i - E; }
    int pos = off[d] + atomicAdd(&cur[d], 1);
    csr_src[pos] = s;
}

// h1 = x @ W1  [N,64] stored bf16; attention logit halves as1/ad1 [N,2] fp32.
__global__ void k_gemm1(const float* __restrict__ x, const float* __restrict__ W1,
                        const float* __restrict__ a_src1, const float* __restrict__ a_dst1,
                        unsigned short* __restrict__ h1b, float* __restrict__ as1,
                        float* __restrict__ ad1, int n) {
    __shared__ float w_lds[64 * 64];
    int t = threadIdx.x;
    for (int i = t; i < 4096; i += 256) w_lds[i] = W1[i];
    __syncthreads();
    int lane = t & 63, wid = t >> 6;
    int head = lane >> 5, cc = lane & 31;
    float asv = a_src1[head * 32 + cc], adv = a_dst1[head * 32 + cc];
    int nwaves = gridDim.x * 4;
    for (int node = blockIdx.x * 4 + wid; node < n; node += nwaves) {
        float xv = x[node * 64 + lane];
        float acc = 0.f;
#pragma unroll
        for (int k = 0; k < 64; ++k) {
            float xk = __shfl(xv, k, 64);
            acc = fmaf(xk, w_lds[k * 64 + lane], acc);
        }
        h1b[node * 64 + lane] = f2bf(acc);
        float ps = acc * asv, pd = acc * adv;
        for (int d = 16; d > 0; d >>= 1) { ps += __shfl_xor(ps, d, 64); pd += __shfl_xor(pd, d, 64); }
        if (cc == 0) { as1[node * 2 + head] = ps; ad1[node * 2 + head] = pd; }
    }
}

// Layer-1 aggregation + bias + exact GELU + (x2 @ W2) + layer-2 logits.
// One wave per node; half-wave per edge row (lane owns 2 channels);
// 8 edges per batch = 4 x (2-edge) steps.
__global__ void __launch_bounds__(256, 4)
k_agg1(const unsigned int* __restrict__ h1w, const float* __restrict__ as1,
       const float* __restrict__ ad1, const float* __restrict__ b1,
       const float* __restrict__ W2, const float* __restrict__ a_src2,
       const float* __restrict__ a_dst2,
       const int* __restrict__ off, const int* __restrict__ csr_src,
       unsigned short* __restrict__ h2b, float* __restrict__ as2,
       float* __restrict__ ad2, int n) {
    __shared__ float w2_lds[64 * 32];
    __shared__ float b1_lds[64];
    __shared__ float av2_lds[64];
    int t = threadIdx.x;
    for (int i = t; i < 2048; i += 256) w2_lds[i] = W2[i];
    if (t < 64) b1_lds[t] = b1[t];
    if (t < 32) av2_lds[t] = a_src2[t];
    else if (t < 64) av2_lds[t] = a_dst2[t - 32];
    __syncthreads();
    int lane = t & 63, wid = t >> 6;
    int h = lane >> 5;          // which edge of the pair
    int c = lane & 31;          // packed word index (channels 2c, 2c+1)
    int head = c >> 4;          // both channels of a word share a head
    int nwaves = gridDim.x * 4;
    for (int node = blockIdx.x * 4 + wid; node < n; node += nwaves) {
        float adh = ad1[node * 2 + head];
        float acc_lo = 0.f, acc_hi = 0.f, wsum = 0.f;
        int p = off[node], pe = off[node + 1];
        for (; p + 8 <= pe; p += 8) {
            int s0 = csr_src[p + 0 + h];
            int s1 = csr_src[p + 2 + h];
            int s2 = csr_src[p + 4 + h];
            int s3 = csr_src[p + 6 + h];
            float a0 = as1[s0 * 2 + head];
            float a1 = as1[s1 * 2 + head];
            float a2 = as1[s2 * 2 + head];
            float a3 = as1[s3 * 2 + head];
            unsigned int u0 = h1w[s0 * 32 + c];
            unsigned int u1 = h1w[s1 * 32 + c];
            unsigned int u2 = h1w[s2 * 32 + c];
            unsigned int u3 = h1w[s3 * 32 + c];
            float e0 = a0 + adh; e0 = e0 > 0.f ? e0 : 0.2f * e0;
            float e1 = a1 + adh; e1 = e1 > 0.f ? e1 : 0.2f * e1;
            float e2 = a2 + adh; e2 = e2 > 0.f ? e2 : 0.2f * e2;
            float e3 = a3 + adh; e3 = e3 > 0.f ? e3 : 0.2f * e3;
            float w0 = __expf(e0), w1 = __expf(e1), w2 = __expf(e2), w3 = __expf(e3);
            wsum += (w0 + w1) + (w2 + w3);
            acc_lo = fmaf(w0, bf_lo(u0), acc_lo); acc_hi = fmaf(w0, bf_hi(u0), acc_hi);
            acc_lo = fmaf(w1, bf_lo(u1), acc_lo); acc_hi = fmaf(w1, bf_hi(u1), acc_hi);
            acc_lo = fmaf(w2, bf_lo(u2), acc_lo); acc_hi = fmaf(w2, bf_hi(u2), acc_hi);
            acc_lo = fmaf(w3, bf_lo(u3), acc_lo); acc_hi = fmaf(w3, bf_hi(u3), acc_hi);
        }
        for (; p < pe; p += 2) {
            if (p + h < pe) {
                int s = csr_src[p + h];
                float e = as1[s * 2 + head] + adh;
                e = e > 0.f ? e : 0.2f * e;
                float w = __expf(e);
                unsigned int u = h1w[s * 32 + c];
                wsum += w;
                acc_lo = fmaf(w, bf_lo(u), acc_lo);
                acc_hi = fmaf(w, bf_hi(u), acc_hi);
            }
        }
        // combine the two half-wave edge streams
        acc_lo += __shfl_xor(acc_lo, 32, 64);
        acc_hi += __shfl_xor(acc_hi, 32, 64);
        wsum   += __shfl_xor(wsum, 32, 64);
        float inv = 1.0f / wsum;
        float g_lo = acc_lo * inv + b1_lds[2 * c];
        float g_hi = acc_hi * inv + b1_lds[2 * c + 1];
        g_lo = 0.5f * g_lo * (1.0f + erff(g_lo * 0.70710678118654752f));
        g_hi = 0.5f * g_hi * (1.0f + erff(g_hi * 0.70710678118654752f));
        // h2lin = gelu_out @ W2 via wave broadcast (channel k lives in lane k>>1)
        int cc = c;   // output column, both halves compute redundantly
        float acc2 = 0.f;
#pragma unroll
        for (int k = 0; k < 64; ++k) {
            float gk = __shfl((k & 1) ? g_hi : g_lo, k >> 1, 64);
            acc2 = fmaf(gk, w2_lds[k * 32 + cc], acc2);
        }
        float ps = acc2 * av2_lds[cc];
        float pd = acc2 * av2_lds[32 + cc];
        for (int d = 16; d > 0; d >>= 1) { ps += __shfl_xor(ps, d, 64); pd += __shfl_xor(pd, d, 64); }
        if (lane < 32) h2b[node * 32 + cc] = f2bf(acc2);
        if (lane == 0) { as2[node] = ps; ad2[node] = pd; }
    }
}

// Layer-2 aggregation: one wave per node, quarter-wave per edge row
// (lane owns 2 of 32 channels); 8 edges per batch = 2 x (4-edge) steps.
__global__ void __launch_bounds__(256, 4)
k_agg2(const unsigned int* __restrict__ h2w, const float* __restrict__ as2,
       const float* __restrict__ ad2, const float* __restrict__ b2,
       const int* __restrict__ off, const int* __restrict__ csr_src,
       float* __restrict__ out, int n) {
    int t = threadIdx.x;
    int lane = t & 63, wid = t >> 6;
    int q = lane >> 4;          // which edge of the quad
    int c = lane & 15;          // packed word index (channels 2c, 2c+1)
    int nwaves = gridDim.x * 4;
    for (int node = blockIdx.x * 4 + wid; node < n; node += nwaves) {
        float adv = ad2[node];
        float acc_lo = 0.f, acc_hi = 0.f, wsum = 0.f;
        int p = off[node], pe = off[node + 1];
        for (; p + 8 <= pe; p += 8) {
            int s0 = csr_src[p + 0 + q];
            int s1 = csr_src[p + 4 + q];
            float a0 = as2[s0];
            float a1 = as2[s1];
            unsigned int u0 = h2w[s0 * 16 + c];
            unsigned int u1 = h2w[s1 * 16 + c];
            float e0 = a0 + adv; e0 = e0 > 0.f ? e0 : 0.2f * e0;
            float e1 = a1 + adv; e1 = e1 > 0.f ? e1 : 0.2f * e1;
            float w0 = __expf(e0), w1 = __expf(e1);
            wsum += w0 + w1;
            acc_lo = fmaf(w0, bf_lo(u0), acc_lo); acc_hi = fmaf(w0, bf_hi(u0), acc_hi);
            acc_lo = fmaf(w1, bf_lo(u1), acc_lo); acc_hi = fmaf(w1, bf_hi(u1), acc_hi);
        }
        for (; p < pe; p += 4) {
            if (p + q < pe) {
                int s = csr_src[p + q];
                float e = as2[s] + adv;
                e = e > 0.f ? e : 0.2f * e;
                float w = __expf(e);
                unsigned int u = h2w[s * 16 + c];
                wsum += w;
                acc_lo = fmaf(w, bf_lo(u), acc_lo);
                acc_hi = fmaf(w, bf_hi(u), acc_hi);
            }
        }
        // combine the four quarter-wave edge streams
        acc_lo += __shfl_xor(acc_lo, 32, 64);
        acc_hi += __shfl_xor(acc_hi, 32, 64);
        wsum   += __shfl_xor(wsum, 32, 64);
        acc_lo += __shfl_xor(acc_lo, 16, 64);
        acc_hi += __shfl_xor(acc_hi, 16, 64);
        wsum   += __shfl_xor(wsum, 16, 64);
        if (lane < 16) {
            float inv = 1.0f / wsum;
            float2 o;
            o.x = acc_lo * inv + b2[2 * c];
            o.y = acc_hi * inv + b2[2 * c + 1];
            *reinterpret_cast<float2*>(&out[node * 32 + 2 * c]) = o;
        }
    }
}

extern "C" void kernel_launch(void* const* d_in, const int* in_sizes, int n_in,
                              void* d_out, int out_size, void* d_ws, size_t ws_size,
                              hipStream_t stream) {
    const float* x      = (const float*)d_in[0];
    const int*   ei     = (const int*)d_in[1];
    const float* W1     = (const float*)d_in[2];
    const float* a_src1 = (const float*)d_in[3];
    const float* a_dst1 = (const float*)d_in[4];
    const float* b1     = (const float*)d_in[5];
    const float* W2     = (const float*)d_in[6];
    const float* a_src2 = (const float*)d_in[7];
    const float* a_dst2 = (const float*)d_in[8];
    const float* b2     = (const float*)d_in[9];
    float* out = (float*)d_out;

    int n   = in_sizes[0] / 64;
    int E   = in_sizes[1] / 2;
    int tot = E + n;

    char* w = (char*)d_ws;
    int* off  = (int*)w; w += sizeof(int) * (size_t)(n + 1);
    int* cnt  = (int*)w; w += sizeof(int) * (size_t)n;
    int* cur  = (int*)w; w += sizeof(int) * (size_t)n;
    int* bsum = (int*)w; w += sizeof(int) * 1024;
    int* csr  = (int*)w; w += sizeof(int) * (size_t)tot;
    unsigned short* h1b = (unsigned short*)w; w += sizeof(unsigned short) * (size_t)n * 64;
    float* as1 = (float*)w; w += sizeof(float) * (size_t)n * 2;
    float* ad1 = (float*)w; w += sizeof(float) * (size_t)n * 2;
    unsigned short* h2b = (unsigned short*)w; w += sizeof(unsigned short) * (size_t)n * 32;
    float* as2v = (float*)w; w += sizeof(float) * (size_t)n;
    float* ad2v = (float*)w; w += sizeof(float) * (size_t)n;

    k_init<<<(n + 255) / 256, 256, 0, stream>>>(cnt, cur, n);
    k_hist<<<(E + 255) / 256, 256, 0, stream>>>(ei, E, cnt);
    int nb = (n + 2047) / 2048;
    k_scan1<<<nb, 256, 0, stream>>>(cnt, off, bsum, n);
    k_scan2<<<1, 1024, 0, stream>>>(bsum, nb);
    k_scan3<<<(n + 255) / 256, 256, 0, stream>>>(off, bsum, n, tot);
    k_scatter<<<(tot + 255) / 256, 256, 0, stream>>>(ei, E, n, off, cur, csr);
    k_gemm1<<<1024, 256, 0, stream>>>(x, W1, a_src1, a_dst1, h1b, as1, ad1, n);
    k_agg1<<<2048, 256, 0, stream>>>((const unsigned int*)h1b, as1, ad1, b1, W2,
                                     a_src2, a_dst2, off, csr, h2b, as2v, ad2v, n);
    k_agg2<<<2048, 256, 0, stream>>>((const unsigned int*)h2b, as2v, ad2v, b2,
                                     off, csr, out, n);
}

// Round 7
// 416.437 us; speedup vs baseline: 1.3135x; 1.0101x over previous
//
#include <hip/hip_runtime.h>
#include <math.h>

// ---------------------------------------------------------------------------
// GAT 2-layer forward. N=100k nodes, E=1.6M edges + N self-loops.
// CSR-by-dst build (hist -> scan -> scatter), then per-node wave aggregation.
// R3: bf16 feature storage. R4: packed-dword gathers + launch bounds.
// R5: W2-GEMM + layer-2 logits split out of agg1 into k_gemm2 (epilogue was
//     ~60% of agg1 VALU); logits pre-scaled by log2e so edge weights use raw
//     v_exp_f32; agg2 gets a 16-edge batch tier.
// (2nd resubmission of R5 -- two consecutive UnresponsiveContainer failures.)
// ---------------------------------------------------------------------------

#define LOG2E 1.4426950408889634f

#if __has_builtin(__builtin_amdgcn_exp2f)
#define EXP2F(x) __builtin_amdgcn_exp2f(x)
#else
#define EXP2F(x) exp2f(x)
#endif

static __device__ __forceinline__ unsigned short f2bf(float f) {
    unsigned int u = __float_as_uint(f);
    unsigned int r = (u + 0x7fffu + ((u >> 16) & 1u)) >> 16;   // RNE
    return (unsigned short)r;
}
static __device__ __forceinline__ float bf_lo(unsigned int w) {
    return __uint_as_float(w << 16);
}
static __device__ __forceinline__ float bf_hi(unsigned int w) {
    return __uint_as_float(w & 0xffff0000u);
}
static __device__ __forceinline__ float leaky(float x) {
    return fmaxf(x, 0.2f * x);
}

__global__ void k_init(int* __restrict__ cnt, int* __restrict__ cur, int n) {
    int i = blockIdx.x * blockDim.x + threadIdx.x;
    if (i < n) { cnt[i] = 1; cur[i] = 0; }   // cnt starts at 1: self-loop
}

__global__ void k_hist(const int* __restrict__ ei, int E, int* __restrict__ cnt) {
    int i = blockIdx.x * blockDim.x + threadIdx.x;
    if (i < E) atomicAdd(&cnt[ei[E + i]], 1);     // ei[1][i] = dst
}

// Per-block (chunk=2048) exclusive scan, block totals to bsum.
__global__ void k_scan1(const int* __restrict__ cnt, int* __restrict__ off,
                        int* __restrict__ bsum, int n) {
    __shared__ int lds[256];
    int t = threadIdx.x;
    int base = blockIdx.x * 2048 + t * 8;
    int v[8]; int s = 0;
#pragma unroll
    for (int j = 0; j < 8; ++j) { int idx = base + j; v[j] = (idx < n) ? cnt[idx] : 0; s += v[j]; }
    lds[t] = s; __syncthreads();
    int inc = s;
    for (int d = 1; d < 256; d <<= 1) {
        int y = (t >= d) ? lds[t - d] : 0;
        __syncthreads();
        inc += y; lds[t] = inc;
        __syncthreads();
    }
    int run = inc - s;
#pragma unroll
    for (int j = 0; j < 8; ++j) { int idx = base + j; if (idx < n) off[idx] = run; run += v[j]; }
    if (t == 255) bsum[blockIdx.x] = inc;
}

__global__ void k_scan2(int* __restrict__ bsum, int nb) {
    __shared__ int lds[1024];
    int t = threadIdx.x;
    int v = (t < nb) ? bsum[t] : 0;
    lds[t] = v; __syncthreads();
    int inc = v;
    for (int d = 1; d < 1024; d <<= 1) {
        int y = (t >= d) ? lds[t - d] : 0;
        __syncthreads();
        inc += y; lds[t] = inc;
        __syncthreads();
    }
    if (t < nb) bsum[t] = inc - v;   // exclusive block prefix
}

__global__ void k_scan3(int* __restrict__ off, const int* __restrict__ bsum, int n, int total) {
    int i = blockIdx.x * blockDim.x + threadIdx.x;
    if (i < n) off[i] += bsum[i / 2048];
    if (i == 0) off[n] = total;
}

__global__ void k_scatter(const int* __restrict__ ei, int E, int n,
                          const int* __restrict__ off, int* __restrict__ cur,
                          int* __restrict__ csr_src) {
    int i = blockIdx.x * blockDim.x + threadIdx.x;
    int total = E + n;
    if (i >= total) return;
    int s, d;
    if (i < E) { s = ei[i]; d = ei[E + i]; } else { s = d = i - E; }
    int pos = off[d] + atomicAdd(&cur[d], 1);
    csr_src[pos] = s;
}

// h1 = x @ W1  [N,64] stored bf16; logit halves as1/ad1 [N,2] fp32 * LOG2E.
__global__ void k_gemm1(const float* __restrict__ x, const float* __restrict__ W1,
                        const float* __restrict__ a_src1, const float* __restrict__ a_dst1,
                        unsigned short* __restrict__ h1b, float* __restrict__ as1,
                        float* __restrict__ ad1, int n) {
    __shared__ float w_lds[64 * 64];
    int t = threadIdx.x;
    for (int i = t; i < 4096; i += 256) w_lds[i] = W1[i];
    __syncthreads();
    int lane = t & 63, wid = t >> 6;
    int head = lane >> 5, cc = lane & 31;
    float asv = a_src1[head * 32 + cc], adv = a_dst1[head * 32 + cc];
    int nwaves = gridDim.x * 4;
    for (int node = blockIdx.x * 4 + wid; node < n; node += nwaves) {
        float xv = x[node * 64 + lane];
        float acc = 0.f;
#pragma unroll
        for (int k = 0; k < 64; ++k) {
            float xk = __shfl(xv, k, 64);
            acc = fmaf(xk, w_lds[k * 64 + lane], acc);
        }
        h1b[node * 64 + lane] = f2bf(acc);
        float ps = acc * asv, pd = acc * adv;
        for (int d = 16; d > 0; d >>= 1) { ps += __shfl_xor(ps, d, 64); pd += __shfl_xor(pd, d, 64); }
        if (cc == 0) { as1[node * 2 + head] = ps * LOG2E; ad1[node * 2 + head] = pd * LOG2E; }
    }
}

// Layer-1 aggregation + bias + exact GELU -> packed bf16 g [N,32 words].
// One wave per node; half-wave per edge row (lane owns 2 channels);
// 8 edges per batch = 4 x (2-edge) steps.
__global__ void __launch_bounds__(256, 4)
k_agg1(const unsigned int* __restrict__ h1w, const float* __restrict__ as1,
       const float* __restrict__ ad1, const float* __restrict__ b1,
       const int* __restrict__ off, const int* __restrict__ csr_src,
       unsigned int* __restrict__ gw, int n) {
    __shared__ float b1_lds[64];
    int t = threadIdx.x;
    if (t < 64) b1_lds[t] = b1[t];
    __syncthreads();
    int lane = t & 63, wid = t >> 6;
    int h = lane >> 5;          // which edge of the pair
    int c = lane & 31;          // packed word index (channels 2c, 2c+1)
    int head = c >> 4;          // both channels of a word share a head
    int nwaves = gridDim.x * 4;
    for (int node = blockIdx.x * 4 + wid; node < n; node += nwaves) {
        float adh = ad1[node * 2 + head];
        float acc_lo = 0.f, acc_hi = 0.f, wsum = 0.f;
        int p = off[node], pe = off[node + 1];
        for (; p + 8 <= pe; p += 8) {
            int s0 = csr_src[p + 0 + h];
            int s1 = csr_src[p + 2 + h];
            int s2 = csr_src[p + 4 + h];
            int s3 = csr_src[p + 6 + h];
            float a0 = as1[s0 * 2 + head];
            float a1 = as1[s1 * 2 + head];
            float a2 = as1[s2 * 2 + head];
            float a3 = as1[s3 * 2 + head];
            unsigned int u0 = h1w[s0 * 32 + c];
            unsigned int u1 = h1w[s1 * 32 + c];
            unsigned int u2 = h1w[s2 * 32 + c];
            unsigned int u3 = h1w[s3 * 32 + c];
            float w0 = EXP2F(leaky(a0 + adh));
            float w1 = EXP2F(leaky(a1 + adh));
            float w2 = EXP2F(leaky(a2 + adh));
            float w3 = EXP2F(leaky(a3 + adh));
            wsum += (w0 + w1) + (w2 + w3);
            acc_lo = fmaf(w0, bf_lo(u0), acc_lo); acc_hi = fmaf(w0, bf_hi(u0), acc_hi);
            acc_lo = fmaf(w1, bf_lo(u1), acc_lo); acc_hi = fmaf(w1, bf_hi(u1), acc_hi);
            acc_lo = fmaf(w2, bf_lo(u2), acc_lo); acc_hi = fmaf(w2, bf_hi(u2), acc_hi);
            acc_lo = fmaf(w3, bf_lo(u3), acc_lo); acc_hi = fmaf(w3, bf_hi(u3), acc_hi);
        }
        for (; p < pe; p += 2) {
            if (p + h < pe) {
                int s = csr_src[p + h];
                float w = EXP2F(leaky(as1[s * 2 + head] + adh));
                unsigned int u = h1w[s * 32 + c];
                wsum += w;
                acc_lo = fmaf(w, bf_lo(u), acc_lo);
                acc_hi = fmaf(w, bf_hi(u), acc_hi);
            }
        }
        // combine the two half-wave edge streams
        acc_lo += __shfl_xor(acc_lo, 32, 64);
        acc_hi += __shfl_xor(acc_hi, 32, 64);
        wsum   += __shfl_xor(wsum, 32, 64);
        float inv = 1.0f / wsum;
        float g_lo = acc_lo * inv + b1_lds[2 * c];
        float g_hi = acc_hi * inv + b1_lds[2 * c + 1];
        g_lo = 0.5f * g_lo * (1.0f + erff(g_lo * 0.70710678118654752f));
        g_hi = 0.5f * g_hi * (1.0f + erff(g_hi * 0.70710678118654752f));
        if (lane < 32)
            gw[node * 32 + c] = (unsigned int)f2bf(g_lo) | ((unsigned int)f2bf(g_hi) << 16);
    }
}

// h2 = g @ W2 [N,32] packed bf16, plus layer-2 logits as2/ad2 (* LOG2E).
// One wave per node; K=64 split across the two half-waves.
__global__ void __launch_bounds__(256, 4)
k_gemm2(const unsigned int* __restrict__ gw, const float* __restrict__ W2,
        const float* __restrict__ a_src2, const float* __restrict__ a_dst2,
        unsigned int* __restrict__ h2w, float* __restrict__ as2,
        float* __restrict__ ad2, int n) {
    __shared__ float w2_lds[64 * 32];
    __shared__ float av2_lds[64];
    int t = threadIdx.x;
    for (int i = t; i < 2048; i += 256) w2_lds[i] = W2[i];
    if (t < 32) av2_lds[t] = a_src2[t] * LOG2E;
    else if (t < 64) av2_lds[t] = a_dst2[t - 32] * LOG2E;
    __syncthreads();
    int lane = t & 63, wid = t >> 6;
    int cc = lane & 31;         // output column
    int kh = lane >> 5;         // K half: lanes 0-31 k=0..31, lanes 32-63 k=32..63
    int kh16 = kh * 16, kh32 = kh * 32;
    int nwaves = gridDim.x * 4;
    for (int node = blockIdx.x * 4 + wid; node < n; node += nwaves) {
        unsigned int u = gw[node * 32 + cc];    // word cc: channels 2cc, 2cc+1
        float acc2 = 0.f;
#pragma unroll
        for (int m = 0; m < 16; ++m) {
            unsigned int uw = __shfl(u, kh16 + m, 32);   // word kh*16+m of this row
            acc2 = fmaf(bf_lo(uw), w2_lds[(kh32 + 2 * m) * 32 + cc], acc2);
            acc2 = fmaf(bf_hi(uw), w2_lds[(kh32 + 2 * m + 1) * 32 + cc], acc2);
        }
        acc2 += __shfl_xor(acc2, 32, 64);       // full K sum, all lanes
        float ps = acc2 * av2_lds[cc];
        float pd = acc2 * av2_lds[32 + cc];
        for (int d = 16; d > 0; d >>= 1) { ps += __shfl_xor(ps, d, 32); pd += __shfl_xor(pd, d, 32); }
        float nb = __shfl_xor(acc2, 1, 32);     // neighbor column value
        if (lane < 32 && !(cc & 1))
            h2w[node * 16 + (cc >> 1)] = (unsigned int)f2bf(acc2) | ((unsigned int)f2bf(nb) << 16);
        if (lane == 0) { as2[node] = ps; ad2[node] = pd; }
    }
}

// Layer-2 aggregation: one wave per node, quarter-wave per edge row
// (lane owns 2 of 32 channels); 16-edge and 8-edge batch tiers.
__global__ void __launch_bounds__(256, 4)
k_agg2(const unsigned int* __restrict__ h2w, const float* __restrict__ as2,
       const float* __restrict__ ad2, const float* __restrict__ b2,
       const int* __restrict__ off, const int* __restrict__ csr_src,
       float* __restrict__ out, int n) {
    int t = threadIdx.x;
    int lane = t & 63, wid = t >> 6;
    int q = lane >> 4;          // which edge of the quad
    int c = lane & 15;          // packed word index (channels 2c, 2c+1)
    int nwaves = gridDim.x * 4;
    for (int node = blockIdx.x * 4 + wid; node < n; node += nwaves) {
        float adv = ad2[node];
        float acc_lo = 0.f, acc_hi = 0.f, wsum = 0.f;
        int p = off[node], pe = off[node + 1];
        for (; p + 16 <= pe; p += 16) {
            int s0 = csr_src[p + 0 + q];
            int s1 = csr_src[p + 4 + q];
            int s2 = csr_src[p + 8 + q];
            int s3 = csr_src[p + 12 + q];
            float a0 = as2[s0], a1 = as2[s1], a2 = as2[s2], a3 = as2[s3];
            unsigned int u0 = h2w[s0 * 16 + c];
            unsigned int u1 = h2w[s1 * 16 + c];
            unsigned int u2 = h2w[s2 * 16 + c];
            unsigned int u3 = h2w[s3 * 16 + c];
            float w0 = EXP2F(leaky(a0 + adv));
            float w1 = EXP2F(leaky(a1 + adv));
            float w2 = EXP2F(leaky(a2 + adv));
            float w3 = EXP2F(leaky(a3 + adv));
            wsum += (w0 + w1) + (w2 + w3);
            acc_lo = fmaf(w0, bf_lo(u0), acc_lo); acc_hi = fmaf(w0, bf_hi(u0), acc_hi);
            acc_lo = fmaf(w1, bf_lo(u1), acc_lo); acc_hi = fmaf(w1, bf_hi(u1), acc_hi);
            acc_lo = fmaf(w2, bf_lo(u2), acc_lo); acc_hi = fmaf(w2, bf_hi(u2), acc_hi);
            acc_lo = fmaf(w3, bf_lo(u3), acc_lo); acc_hi = fmaf(w3, bf_hi(u3), acc_hi);
        }
        for (; p + 8 <= pe; p += 8) {
            int s0 = csr_src[p + 0 + q];
            int s1 = csr_src[p + 4 + q];
            float a0 = as2[s0], a1 = as2[s1];
            unsigned int u0 = h2w[s0 * 16 + c];
            unsigned int u1 = h2w[s1 * 16 + c];
            float w0 = EXP2F(leaky(a0 + adv));
            float w1 = EXP2F(leaky(a1 + adv));
            wsum += w0 + w1;
            acc_lo = fmaf(w0, bf_lo(u0), acc_lo); acc_hi = fmaf(w0, bf_hi(u0), acc_hi);
            acc_lo = fmaf(w1, bf_lo(u1), acc_lo); acc_hi = fmaf(w1, bf_hi(u1), acc_hi);
        }
        for (; p < pe; p += 4) {
            if (p + q < pe) {
                int s = csr_src[p + q];
                float w = EXP2F(leaky(as2[s] + adv));
                unsigned int u = h2w[s * 16 + c];
                wsum += w;
                acc_lo = fmaf(w, bf_lo(u), acc_lo);
                acc_hi = fmaf(w, bf_hi(u), acc_hi);
            }
        }
        // combine the four quarter-wave edge streams
        acc_lo += __shfl_xor(acc_lo, 32, 64);
        acc_hi += __shfl_xor(acc_hi, 32, 64);
        wsum   += __shfl_xor(wsum, 32, 64);
        acc_lo += __shfl_xor(acc_lo, 16, 64);
        acc_hi += __shfl_xor(acc_hi, 16, 64);
        wsum   += __shfl_xor(wsum, 16, 64);
        if (lane < 16) {
            float inv = 1.0f / wsum;
            float2 o;
            o.x = acc_lo * inv + b2[2 * c];
            o.y = acc_hi * inv + b2[2 * c + 1];
            *reinterpret_cast<float2*>(&out[node * 32 + 2 * c]) = o;
        }
    }
}

extern "C" void kernel_launch(void* const* d_in, const int* in_sizes, int n_in,
                              void* d_out, int out_size, void* d_ws, size_t ws_size,
                              hipStream_t stream) {
    const float* x      = (const float*)d_in[0];
    const int*   ei     = (const int*)d_in[1];
    const float* W1     = (const float*)d_in[2];
    const float* a_src1 = (const float*)d_in[3];
    const float* a_dst1 = (const float*)d_in[4];
    const float* b1     = (const float*)d_in[5];
    const float* W2     = (const float*)d_in[6];
    const float* a_src2 = (const float*)d_in[7];
    const float* a_dst2 = (const float*)d_in[8];
    const float* b2     = (const float*)d_in[9];
    float* out = (float*)d_out;

    int n   = in_sizes[0] / 64;
    int E   = in_sizes[1] / 2;
    int tot = E + n;

    char* w = (char*)d_ws;
    int* off  = (int*)w; w += sizeof(int) * (size_t)(n + 1);
    int* cnt  = (int*)w; w += sizeof(int) * (size_t)n;
    int* cur  = (int*)w; w += sizeof(int) * (size_t)n;
    int* bsum = (int*)w; w += sizeof(int) * 1024;
    int* csr  = (int*)w; w += sizeof(int) * (size_t)tot;
    unsigned short* h1b = (unsigned short*)w; w += sizeof(unsigned short) * (size_t)n * 64;
    float* as1 = (float*)w; w += sizeof(float) * (size_t)n * 2;
    float* ad1 = (float*)w; w += sizeof(float) * (size_t)n * 2;
    unsigned int* gw = (unsigned int*)w; w += sizeof(unsigned int) * (size_t)n * 32;
    float* as2v = (float*)w; w += sizeof(float) * (size_t)n;
    float* ad2v = (float*)w; w += sizeof(float) * (size_t)n;
    // h2 (packed bf16, [n,16 words]) aliases h1b: h1b is dead once k_agg1 completes,
    // and k_gemm2 (which writes h2) only launches after k_agg1 in stream order.
    unsigned int* h2w = (unsigned int*)h1b;

    k_init<<<(n + 255) / 256, 256, 0, stream>>>(cnt, cur, n);
    k_hist<<<(E + 255) / 256, 256, 0, stream>>>(ei, E, cnt);
    int nb = (n + 2047) / 2048;
    k_scan1<<<nb, 256, 0, stream>>>(cnt, off, bsum, n);
    k_scan2<<<1, 1024, 0, stream>>>(bsum, nb);
    k_scan3<<<(n + 255) / 256, 256, 0, stream>>>(off, bsum, n, tot);
    k_scatter<<<(tot + 255) / 256, 256, 0, stream>>>(ei, E, n, off, cur, csr);
    k_gemm1<<<1024, 256, 0, stream>>>(x, W1, a_src1, a_dst1, h1b, as1, ad1, n);
    k_agg1<<<2048, 256, 0, stream>>>((const unsigned int*)h1b, as1, ad1, b1,
                                     off, csr, gw, n);
    k_gemm2<<<1024, 256, 0, stream>>>(gw, W2, a_src2, a_dst2, h2w, as2v, ad2v, n);
    k_agg2<<<2048, 256, 0, stream>>>(h2w, as2v, ad2v, b2, off, csr, out, n);
}